// Round 8
// baseline (17.808 us; speedup 1.0000x reference)
//
#include <hip/hip_runtime.h>
#include <hip/hip_bf16.h>

#define DDIM 128
#define K2_BLOCKS 256
#define K2_THREADS 1024
#define MAX_XS_UNITS 98    // 98 KB: xs table (<= 50176 bf16 nodes)
#define TABB_UNITS   61    // 61 KB: xd-lo table (nodes [0, 31232))
// total static LDS = (98+61)*1024 = 162816 B <= 163840 B/CU

typedef float vf4 __attribute__((ext_vector_type(4)));
typedef int   vi4 __attribute__((ext_vector_type(4)));

__device__ __forceinline__ float bf16_to_f32(unsigned short u) {
    return __uint_as_float(((unsigned int)u) << 16);
}

// Async global->LDS DMA, 16 B per lane (1 KB per wave-issue).
// HW rule: LDS dest = wave-uniform base + lane*16; global SOURCE is
// per-lane and MUST carry the lane*16 offset (round-7 bug: omitted it ->
// each lane replicated the unit's first 16B).
__device__ __forceinline__ void lds_dma16(const void* g, void* l) {
    __builtin_amdgcn_global_load_lds(
        (const __attribute__((address_space(1))) unsigned int*)g,
        (__attribute__((address_space(3))) unsigned int*)l,
        16, 0, 0);
}

// Node projection: one wave covers EIGHT rows (two quads). c = lane&15
// covers dims [8c, 8c+7]; r = lane>>4 picks the row within each quad.
// 4 x 16B loads in flight per lane, 4 interleaved shuffle-reduce chains.
__global__ __launch_bounds__(256) void node_proj_kernel(
    const float* __restrict__ x,
    const float* __restrict__ W,
    __hip_bfloat16* __restrict__ xs,
    __hip_bfloat16* __restrict__ xd,
    int n_nodes)
{
    const int tib  = threadIdx.x;
    const int lane = tib & 63;
    const int w    = blockIdx.x * 4 + (tib >> 6);   // wave id, 8 rows each
    const int c    = lane & 15;   // 16 lanes per row
    const int r    = lane >> 4;   // row within quad

    const vf4 wsA = *reinterpret_cast<const vf4*>(W + c * 8);
    const vf4 wsB = *reinterpret_cast<const vf4*>(W + c * 8 + 4);
    const vf4 wdA = *reinterpret_cast<const vf4*>(W + DDIM + c * 8);
    const vf4 wdB = *reinterpret_cast<const vf4*>(W + DDIM + c * 8 + 4);

    const int ra = 8 * w + r;       // rows of quad A
    const int rb = ra + 4;          // rows of quad B
    vf4 a0 = {0,0,0,0}, a1 = {0,0,0,0};
    vf4 b0 = {0,0,0,0}, b1 = {0,0,0,0};
    if (ra < n_nodes) {
        const vf4* pa = reinterpret_cast<const vf4*>(x + (size_t)ra * DDIM + c * 8);
        a0 = __builtin_nontemporal_load(pa);
        a1 = __builtin_nontemporal_load(pa + 1);
    }
    if (rb < n_nodes) {
        const vf4* pb = reinterpret_cast<const vf4*>(x + (size_t)rb * DDIM + c * 8);
        b0 = __builtin_nontemporal_load(pb);
        b1 = __builtin_nontemporal_load(pb + 1);
    }

    float sA = a0.x*wsA.x + a0.y*wsA.y + a0.z*wsA.z + a0.w*wsA.w
             + a1.x*wsB.x + a1.y*wsB.y + a1.z*wsB.z + a1.w*wsB.w;
    float dA = a0.x*wdA.x + a0.y*wdA.y + a0.z*wdA.z + a0.w*wdA.w
             + a1.x*wdB.x + a1.y*wdB.y + a1.z*wdB.z + a1.w*wdB.w;
    float sB = b0.x*wsA.x + b0.y*wsA.y + b0.z*wsA.z + b0.w*wsA.w
             + b1.x*wsB.x + b1.y*wsB.y + b1.z*wsB.z + b1.w*wsB.w;
    float dB = b0.x*wdA.x + b0.y*wdA.y + b0.z*wdA.z + b0.w*wdA.w
             + b1.x*wdB.x + b1.y*wdB.y + b1.z*wdB.z + b1.w*wdB.w;

    #pragma unroll
    for (int m = 8; m >= 1; m >>= 1) {
        sA += __shfl_xor(sA, m, 64);
        dA += __shfl_xor(dA, m, 64);
        sB += __shfl_xor(sB, m, 64);
        dB += __shfl_xor(dB, m, 64);
    }
    if (c == 0) {
        if (ra < n_nodes) {
            xs[ra] = __float2bfloat16(sA);
            xd[ra] = __float2bfloat16(dA);
        }
        if (rb < n_nodes) {
            xs[rb] = __float2bfloat16(sB);
            xd[rb] = __float2bfloat16(dB);
        }
    }
}

// Split-table edge scorer:
//   tabA (98 KB): full xs table.   tabB (61 KB): xd for nodes [0, SPLIT).
//   Phase 0: DMA both (159 KB L2) -- hidden under the 12.8 MB src/dst fetch.
//   Phase 1: xs gathers (tabA) + xd-lo gathers (tabB, t < SPLIT).
//   Restage: only xd-hi (37 KB) over tabA -> exposed stage 0.73us -> 0.28us.
//   Phase 2: xd-hi gathers (t >= SPLIT), combine, single store.
// Total staging traffic unchanged (196 KB/block); purely rescheduled.
__global__ __launch_bounds__(K2_THREADS) void edge_lds_kernel(
    const int* __restrict__ src,
    const int* __restrict__ dst,
    const unsigned char* __restrict__ xs_b,   // xs table, units KB
    const unsigned char* __restrict__ xd_b,   // xd table, units KB
    const float* __restrict__ b,
    float* __restrict__ out,
    int units, int loU, int hiU, int split, int n_quads, int n_edges)
{
    __shared__ __align__(16) unsigned char lds[(MAX_XS_UNITS + TABB_UNITS) * 1024];
    unsigned char* tabA = lds;
    unsigned char* tabB = lds + MAX_XS_UNITS * 1024;
    const unsigned short* tA16 = reinterpret_cast<const unsigned short*>(tabA);
    const unsigned short* tB16 = reinterpret_cast<const unsigned short*>(tabB);

    const int tid = threadIdx.x;
    const int wv  = tid >> 6;     // wave in block (0..15)
    const int ln  = tid & 63;
    const int gid = blockIdx.x * K2_THREADS + tid;
    const int T   = K2_BLOCKS * K2_THREADS;

    // ---- issue src/dst index loads first: HBM latency overlaps staging ----
    const int q0 = gid, q1 = gid + T;
    const bool h0 = q0 < n_quads, h1 = q1 < n_quads;
    vi4 s0 = {0,0,0,0}, s1 = {0,0,0,0};
    vi4 t0 = {0,0,0,0}, t1 = {0,0,0,0};
    if (h0) {
        s0 = __builtin_nontemporal_load(reinterpret_cast<const vi4*>(src) + q0);
        t0 = __builtin_nontemporal_load(reinterpret_cast<const vi4*>(dst) + q0);
    }
    if (h1) {
        s1 = __builtin_nontemporal_load(reinterpret_cast<const vi4*>(src) + q1);
        t1 = __builtin_nontemporal_load(reinterpret_cast<const vi4*>(dst) + q1);
    }
    const float bb = b[0];
    // scalar tail (n_edges % 4) indices
    const int tail = n_edges & 3;
    int te = -1, ts = 0, td = 0; float pt = 0.f;
    if (blockIdx.x == 0 && tid < tail) {
        te = (n_quads << 2) + tid;
        ts = src[te];
        td = dst[te];
    }

    // ---- phase 0: DMA xs -> tabA, xd-lo -> tabB (hidden under fetch) ----
    for (int i = wv; i < units; i += K2_THREADS / 64)
        lds_dma16(xs_b + (size_t)i * 1024 + ln * 16, tabA + i * 1024);
    for (int i = wv; i < loU; i += K2_THREADS / 64)
        lds_dma16(xd_b + (size_t)i * 1024 + ln * 16, tabB + i * 1024);
    __syncthreads();   // drains vmcnt: DMA + src/dst loads complete

    // ---- phase 1: xs gathers + xd-lo gathers (t < split) ----
    vf4 p0 = {0,0,0,0}, p1 = {0,0,0,0};
    if (h0) {
        p0.x = bf16_to_f32(tA16[s0.x]) + bb;
        p0.y = bf16_to_f32(tA16[s0.y]) + bb;
        p0.z = bf16_to_f32(tA16[s0.z]) + bb;
        p0.w = bf16_to_f32(tA16[s0.w]) + bb;
        if (t0.x < split) p0.x += bf16_to_f32(tB16[t0.x]);
        if (t0.y < split) p0.y += bf16_to_f32(tB16[t0.y]);
        if (t0.z < split) p0.z += bf16_to_f32(tB16[t0.z]);
        if (t0.w < split) p0.w += bf16_to_f32(tB16[t0.w]);
    }
    if (h1) {
        p1.x = bf16_to_f32(tA16[s1.x]) + bb;
        p1.y = bf16_to_f32(tA16[s1.y]) + bb;
        p1.z = bf16_to_f32(tA16[s1.z]) + bb;
        p1.w = bf16_to_f32(tA16[s1.w]) + bb;
        if (t1.x < split) p1.x += bf16_to_f32(tB16[t1.x]);
        if (t1.y < split) p1.y += bf16_to_f32(tB16[t1.y]);
        if (t1.z < split) p1.z += bf16_to_f32(tB16[t1.z]);
        if (t1.w < split) p1.w += bf16_to_f32(tB16[t1.w]);
    }
    if (te >= 0) {
        pt = bf16_to_f32(tA16[ts]) + bb;
        if (td < split) pt += bf16_to_f32(tB16[td]);
    }

    // ---- restage: xd-hi (37 KB) over tabA ----
    __syncthreads();   // all waves done reading tabA
    for (int i = wv; i < hiU; i += K2_THREADS / 64)
        lds_dma16(xd_b + (size_t)(loU + i) * 1024 + ln * 16, tabA + i * 1024);
    __syncthreads();   // drain DMA

    // ---- phase 2: xd-hi gathers (t >= split), combine, single store ----
    if (h0) {
        if (t0.x >= split) p0.x += bf16_to_f32(tA16[t0.x - split]);
        if (t0.y >= split) p0.y += bf16_to_f32(tA16[t0.y - split]);
        if (t0.z >= split) p0.z += bf16_to_f32(tA16[t0.z - split]);
        if (t0.w >= split) p0.w += bf16_to_f32(tA16[t0.w - split]);
        __builtin_nontemporal_store(p0, reinterpret_cast<vf4*>(out) + q0);
    }
    if (h1) {
        if (t1.x >= split) p1.x += bf16_to_f32(tA16[t1.x - split]);
        if (t1.y >= split) p1.y += bf16_to_f32(tA16[t1.y - split]);
        if (t1.z >= split) p1.z += bf16_to_f32(tA16[t1.z - split]);
        if (t1.w >= split) p1.w += bf16_to_f32(tA16[t1.w - split]);
        __builtin_nontemporal_store(p1, reinterpret_cast<vf4*>(out) + q1);
    }
    if (te >= 0) {
        if (td >= split) pt += bf16_to_f32(tA16[td - split]);
        out[te] = pt;
    }
}

extern "C" void kernel_launch(void* const* d_in, const int* in_sizes, int n_in,
                              void* d_out, int out_size, void* d_ws, size_t ws_size,
                              hipStream_t stream) {
    const float* x   = (const float*)d_in[0];
    const int*   src = (const int*)d_in[1];
    const int*   dst = (const int*)d_in[2];
    const float* W   = (const float*)d_in[3];
    const float* b   = (const float*)d_in[4];
    float* out = (float*)d_out;

    const int n_nodes = in_sizes[0] / DDIM;
    const int n_edges = in_sizes[1];

    // table layout in 1 KB DMA units: xs at [0, units KB), xd after it
    const int units = (n_nodes * 2 + 1023) >> 10;    // KB units per table
    const int loU   = units < TABB_UNITS ? units : TABB_UNITS;
    const int hiU   = units - loU;
    const int split = loU * 512;                     // bf16 entries in tabB
    unsigned char* wsb = (unsigned char*)d_ws;
    __hip_bfloat16* xs = (__hip_bfloat16*)wsb;
    __hip_bfloat16* xd = (__hip_bfloat16*)(wsb + (size_t)units * 1024);

    // K1: 8-rows-per-wave projection, exact cover (32 rows/block).
    const int k1_blocks = (n_nodes + 31) >> 5;
    node_proj_kernel<<<k1_blocks, 256, 0, stream>>>(x, W, xs, xd, n_nodes);

    // K2: split-table LDS edge scorer.
    const int n_quads = n_edges >> 2;
    edge_lds_kernel<<<K2_BLOCKS, K2_THREADS, 0, stream>>>(
        src, dst, wsb, wsb + (size_t)units * 1024, b, out,
        units, loU, hiU, split, n_quads, n_edges);
}

// Round 9
// 16.941 us; speedup vs baseline: 1.0511x; 1.0511x over previous
//
#include <hip/hip_runtime.h>
#include <hip/hip_bf16.h>

#define DDIM 128
#define K2_BLOCKS 256
#define K2_THREADS 1024
#define MAX_TAB32 25088   // 50176 bf16 entries = 100352 B LDS = 98 KB DMA units

typedef float vf4 __attribute__((ext_vector_type(4)));
typedef int   vi4 __attribute__((ext_vector_type(4)));

__device__ __forceinline__ float bf16_to_f32(unsigned short u) {
    return __uint_as_float(((unsigned int)u) << 16);
}

// Async global->LDS DMA, 16 B per lane (1 KB per wave-issue).
// HW rule: LDS dest = wave-uniform base + lane*16; global SOURCE is
// per-lane and must carry the lane*16 offset.
__device__ __forceinline__ void lds_dma16(const void* g, void* l) {
    __builtin_amdgcn_global_load_lds(
        (const __attribute__((address_space(1))) unsigned int*)g,
        (__attribute__((address_space(3))) unsigned int*)l,
        16, 0, 0);
}

// Node projection: one wave covers EIGHT rows (two quads). c = lane&15
// covers dims [8c, 8c+7]; r = lane>>4 picks the row within each quad.
// 4 x 16B loads in flight per lane and 4 interleaved shuffle-reduce
// chains (4-way ILP on the ds-swizzle latency). Predicated row guards
// subsume all tails.
__global__ __launch_bounds__(256) void node_proj_kernel(
    const float* __restrict__ x,
    const float* __restrict__ W,
    __hip_bfloat16* __restrict__ xs,
    __hip_bfloat16* __restrict__ xd,
    int n_nodes)
{
    const int tib  = threadIdx.x;
    const int lane = tib & 63;
    const int w    = blockIdx.x * 4 + (tib >> 6);   // wave id, 8 rows each
    const int c    = lane & 15;   // 16 lanes per row
    const int r    = lane >> 4;   // row within quad

    const vf4 wsA = *reinterpret_cast<const vf4*>(W + c * 8);
    const vf4 wsB = *reinterpret_cast<const vf4*>(W + c * 8 + 4);
    const vf4 wdA = *reinterpret_cast<const vf4*>(W + DDIM + c * 8);
    const vf4 wdB = *reinterpret_cast<const vf4*>(W + DDIM + c * 8 + 4);

    const int ra = 8 * w + r;       // rows of quad A
    const int rb = ra + 4;          // rows of quad B
    vf4 a0 = {0,0,0,0}, a1 = {0,0,0,0};
    vf4 b0 = {0,0,0,0}, b1 = {0,0,0,0};
    if (ra < n_nodes) {
        const vf4* pa = reinterpret_cast<const vf4*>(x + (size_t)ra * DDIM + c * 8);
        a0 = __builtin_nontemporal_load(pa);
        a1 = __builtin_nontemporal_load(pa + 1);
    }
    if (rb < n_nodes) {
        const vf4* pb = reinterpret_cast<const vf4*>(x + (size_t)rb * DDIM + c * 8);
        b0 = __builtin_nontemporal_load(pb);
        b1 = __builtin_nontemporal_load(pb + 1);
    }

    float sA = a0.x*wsA.x + a0.y*wsA.y + a0.z*wsA.z + a0.w*wsA.w
             + a1.x*wsB.x + a1.y*wsB.y + a1.z*wsB.z + a1.w*wsB.w;
    float dA = a0.x*wdA.x + a0.y*wdA.y + a0.z*wdA.z + a0.w*wdA.w
             + a1.x*wdB.x + a1.y*wdB.y + a1.z*wdB.z + a1.w*wdB.w;
    float sB = b0.x*wsA.x + b0.y*wsA.y + b0.z*wsA.z + b0.w*wsA.w
             + b1.x*wsB.x + b1.y*wsB.y + b1.z*wsB.z + b1.w*wsB.w;
    float dB = b0.x*wdA.x + b0.y*wdA.y + b0.z*wdA.z + b0.w*wdA.w
             + b1.x*wdB.x + b1.y*wdB.y + b1.z*wdB.z + b1.w*wdB.w;

    #pragma unroll
    for (int m = 8; m >= 1; m >>= 1) {
        sA += __shfl_xor(sA, m, 64);
        dA += __shfl_xor(dA, m, 64);
        sB += __shfl_xor(sB, m, 64);
        dB += __shfl_xor(dB, m, 64);
    }
    if (c == 0) {
        if (ra < n_nodes) {
            xs[ra] = __float2bfloat16(sA);
            xd[ra] = __float2bfloat16(dA);
        }
        if (rb < n_nodes) {
            xs[rb] = __float2bfloat16(sB);
            xd[rb] = __float2bfloat16(dB);
        }
    }
}

// Edge scores with LDS-resident tables. Swap structure (stage xs ->
// partials -> restage xd -> finish); staging is pure async DMA
// (global_load_lds x16B): no VGPR round-trip, no staging VALU. Tables
// laid out in 1KB DMA units; each wave issues <=7 DMA ops per table and
// __syncthreads() drains them. Proven in this session: LDS gathers beat
// direct L2 gathers ~4x (r4); unconditional-gather swap beats split-table
// conditional gathers (r8); reg-held tables spill (r1); grid-sync fusion
// costs ~115us (r3).
__global__ __launch_bounds__(K2_THREADS) void edge_lds_kernel(
    const int* __restrict__ src,
    const int* __restrict__ dst,
    const unsigned char* __restrict__ xs_b,   // table base, nb KB
    const unsigned char* __restrict__ xd_b,   // table base, nb KB
    const float* __restrict__ b,
    float* __restrict__ out,
    int nb, int n_quads, int n_edges)
{
    __shared__ __align__(16) unsigned short tab[MAX_TAB32 * 2];
    unsigned char* tabb = reinterpret_cast<unsigned char*>(tab);

    const int tid = threadIdx.x;
    const int wv  = tid >> 6;     // wave in block (0..15)
    const int ln  = tid & 63;
    const int gid = blockIdx.x * K2_THREADS + tid;
    const int T   = K2_BLOCKS * K2_THREADS;

    // ---- issue src/dst index loads first: HBM latency overlaps staging ----
    const int q0 = gid, q1 = gid + T;
    const bool h0 = q0 < n_quads, h1 = q1 < n_quads;
    vi4 s0 = {0,0,0,0}, s1 = {0,0,0,0};
    vi4 t0 = {0,0,0,0}, t1 = {0,0,0,0};
    if (h0) {
        s0 = __builtin_nontemporal_load(reinterpret_cast<const vi4*>(src) + q0);
        t0 = __builtin_nontemporal_load(reinterpret_cast<const vi4*>(dst) + q0);
    }
    if (h1) {
        s1 = __builtin_nontemporal_load(reinterpret_cast<const vi4*>(src) + q1);
        t1 = __builtin_nontemporal_load(reinterpret_cast<const vi4*>(dst) + q1);
    }
    const float bb = b[0];

    // ---- stage xs table: async DMA, 1 KB per wave-issue ----
    for (int i = wv; i < nb; i += K2_THREADS / 64)
        lds_dma16(xs_b + (size_t)i * 1024 + ln * 16, tabb + i * 1024);
    __syncthreads();   // drains vmcnt(0): DMA + src/dst loads complete

    // ---- phase 1: partials from xs gathers; dst indices kept in regs ----
    vf4 p0 = {0,0,0,0}, p1 = {0,0,0,0};
    if (h0) {
        p0.x = bf16_to_f32(tab[s0.x]) + bb;
        p0.y = bf16_to_f32(tab[s0.y]) + bb;
        p0.z = bf16_to_f32(tab[s0.z]) + bb;
        p0.w = bf16_to_f32(tab[s0.w]) + bb;
    }
    if (h1) {
        p1.x = bf16_to_f32(tab[s1.x]) + bb;
        p1.y = bf16_to_f32(tab[s1.y]) + bb;
        p1.z = bf16_to_f32(tab[s1.z]) + bb;
        p1.w = bf16_to_f32(tab[s1.w]) + bb;
    }
    // scalar tail (n_edges % 4)
    const int tail = n_edges & 3;
    int te = -1; float pt = 0.f; int td = 0;
    if (blockIdx.x == 0 && tid < tail) {
        te = (n_quads << 2) + tid;
        td = dst[te];
        pt = bf16_to_f32(tab[src[te]]) + bb;
    }

    // ---- swap table: xd via async DMA into the same LDS ----
    __syncthreads();   // all waves done reading xs
    for (int i = wv; i < nb; i += K2_THREADS / 64)
        lds_dma16(xd_b + (size_t)i * 1024 + ln * 16, tabb + i * 1024);
    __syncthreads();   // drains DMA

    // ---- phase 2: finish with xd gathers, single store ----
    if (h0) {
        vf4 o;
        o.x = p0.x + bf16_to_f32(tab[t0.x]);
        o.y = p0.y + bf16_to_f32(tab[t0.y]);
        o.z = p0.z + bf16_to_f32(tab[t0.z]);
        o.w = p0.w + bf16_to_f32(tab[t0.w]);
        __builtin_nontemporal_store(o, reinterpret_cast<vf4*>(out) + q0);
    }
    if (h1) {
        vf4 o;
        o.x = p1.x + bf16_to_f32(tab[t1.x]);
        o.y = p1.y + bf16_to_f32(tab[t1.y]);
        o.z = p1.z + bf16_to_f32(tab[t1.z]);
        o.w = p1.w + bf16_to_f32(tab[t1.w]);
        __builtin_nontemporal_store(o, reinterpret_cast<vf4*>(out) + q1);
    }
    if (te >= 0) out[te] = pt + bf16_to_f32(tab[td]);
}

extern "C" void kernel_launch(void* const* d_in, const int* in_sizes, int n_in,
                              void* d_out, int out_size, void* d_ws, size_t ws_size,
                              hipStream_t stream) {
    const float* x   = (const float*)d_in[0];
    const int*   src = (const int*)d_in[1];
    const int*   dst = (const int*)d_in[2];
    const float* W   = (const float*)d_in[3];
    const float* b   = (const float*)d_in[4];
    float* out = (float*)d_out;

    const int n_nodes = in_sizes[0] / DDIM;
    const int n_edges = in_sizes[1];

    // table layout in 1 KB DMA units: xs at [0, nb KB), xd at [nb, 2*nb KB)
    const int n32 = (n_nodes + 1) >> 1;
    const int nb  = (n32 * 4 + 1023) >> 10;          // KB units per table
    unsigned char* wsb = (unsigned char*)d_ws;
    __hip_bfloat16* xs = (__hip_bfloat16*)wsb;
    __hip_bfloat16* xd = (__hip_bfloat16*)(wsb + (size_t)nb * 1024);

    // K1: 8-rows-per-wave projection, exact cover (32 rows/block).
    const int k1_blocks = (n_nodes + 31) >> 5;
    node_proj_kernel<<<k1_blocks, 256, 0, stream>>>(x, W, xs, xd, n_nodes);

    // K2: LDS-table edge scorer with async-DMA staging.
    const int n_quads = n_edges >> 2;
    edge_lds_kernel<<<K2_BLOCKS, K2_THREADS, 0, stream>>>(
        src, dst, wsb, wsb + (size_t)nb * 1024, b, out,
        nb, n_quads, n_edges);
}